// Round 3
// baseline (370.753 us; speedup 1.0000x reference)
//
#include <hip/hip_runtime.h>

// Winograd F(2x2,3x3), fixed Laplacian filter. F = G@FILT@G^T precomputed:
//   [[ 0.0, -0.5,  0.5,  0.0],
//    [-0.5,  0.0, -1.0, -0.5],
//    [ 0.5, -1.0,  2.0,  0.5],
//    [ 0.0, -0.5,  0.5,  0.0]]
//
// R2 post-mortem: LDS staging was neutral vs R0's direct per-thread loads
// (365 vs 368 us) and the kernel never appears in rocprof top-5 (all
// ~160us harness 1GiB fills) => kernel < 160us; reported dur_us is
// dominated by fixed harness restore/poison work. R3 probe: minimal
// instruction count (no LDS, no barrier) + nontemporal load/store hints
// for the pure streaming pattern. If neutral again -> kernel is at the
// ~53us HBM roofline and dur_us is harness-floored.

typedef float v4f __attribute__((ext_vector_type(4)));

__global__ __launch_bounds__(256) void winograd_tile_kernel(
    const v4f* __restrict__ x4,   // [n_tiles*4] rows of 4 floats
    v4f* __restrict__ out4,       // [n_tiles] (2x2 output per tile)
    int n_tiles)
{
    int t = blockIdx.x * blockDim.x + threadIdx.x;
    if (t >= n_tiles) return;

    // One 64B cache line per thread, fully consumed (4 x 16B nt loads).
    const v4f* p = x4 + 4ll * t;
    v4f r0 = __builtin_nontemporal_load(p + 0);
    v4f r1 = __builtin_nontemporal_load(p + 1);
    v4f r2 = __builtin_nontemporal_load(p + 2);
    v4f r3 = __builtin_nontemporal_load(p + 3);

    float xin[4][4] = {
        {r0.x, r0.y, r0.z, r0.w},
        {r1.x, r1.y, r1.z, r1.w},
        {r2.x, r2.y, r2.z, r2.w},
        {r3.x, r3.y, r3.z, r3.w},
    };

    // Bx = B @ x  (B = [[1,0,-1,0],[0,1,1,0],[0,-1,1,0],[0,1,0,-1]])
    float bx[4][4];
#pragma unroll
    for (int c = 0; c < 4; ++c) {
        bx[0][c] = xin[0][c] - xin[2][c];
        bx[1][c] = xin[1][c] + xin[2][c];
        bx[2][c] = xin[2][c] - xin[1][c];
        bx[3][c] = xin[1][c] - xin[3][c];
    }

    // D = Bx @ B^T
    float D[4][4];
#pragma unroll
    for (int r = 0; r < 4; ++r) {
        D[r][0] = bx[r][0] - bx[r][2];
        D[r][1] = bx[r][1] + bx[r][2];
        D[r][2] = bx[r][2] - bx[r][1];
        D[r][3] = bx[r][1] - bx[r][3];
    }

    // Y = F .* D (corners of F are zero -> only 12 products)
    float Y[4][4];
    Y[0][0] = 0.0f;
    Y[0][1] = -0.5f * D[0][1];
    Y[0][2] =  0.5f * D[0][2];
    Y[0][3] = 0.0f;
    Y[1][0] = -0.5f * D[1][0];
    Y[1][1] = 0.0f;
    Y[1][2] = -1.0f * D[1][2];
    Y[1][3] = -0.5f * D[1][3];
    Y[2][0] =  0.5f * D[2][0];
    Y[2][1] = -1.0f * D[2][1];
    Y[2][2] =  2.0f * D[2][2];
    Y[2][3] =  0.5f * D[2][3];
    Y[3][0] = 0.0f;
    Y[3][1] = -0.5f * D[3][1];
    Y[3][2] =  0.5f * D[3][2];
    Y[3][3] = 0.0f;

    // AY = A @ Y  (A = [[1,1,1,0],[0,1,-1,-1]])
    float ay0[4], ay1[4];
#pragma unroll
    for (int c = 0; c < 4; ++c) {
        ay0[c] = Y[0][c] + Y[1][c] + Y[2][c];
        ay1[c] = Y[1][c] - Y[2][c] - Y[3][c];
    }

    // O = AY @ A^T -> 2x2, one coalesced nt float4 store
    v4f o;
    o.x = ay0[0] + ay0[1] + ay0[2];
    o.y = ay0[1] - ay0[2] - ay0[3];
    o.z = ay1[0] + ay1[1] + ay1[2];
    o.w = ay1[1] - ay1[2] - ay1[3];

    __builtin_nontemporal_store(o, out4 + t);
}

extern "C" void kernel_launch(void* const* d_in, const int* in_sizes, int n_in,
                              void* d_out, int out_size, void* d_ws, size_t ws_size,
                              hipStream_t stream)
{
    const v4f* x4 = (const v4f*)d_in[0];
    v4f* out4 = (v4f*)d_out;
    int n_tiles = in_sizes[0] / 16;

    int block = 256;
    int grid = (n_tiles + block - 1) / block;
    winograd_tile_kernel<<<grid, block, 0, stream>>>(x4, out4, n_tiles);
}